// Round 1
// baseline (898.757 us; speedup 1.0000x reference)
//
#include <hip/hip_runtime.h>
#include <hip/hip_bf16.h>
#include <stdint.h>

// ---------------- problem constants ----------------
#define T_TOK 8192          // 4*2048 tokens
#define HID   2048          // hidden
#define IM    1024          // intermediate (GLU output)
#define NE    8             // experts
#define NASSIGN (T_TOK*2)   // top-2 assignments

typedef __attribute__((ext_vector_type(8))) short bf16x8;   // 8 bf16 in 4 VGPRs
typedef __attribute__((ext_vector_type(4))) float f32x4;    // MFMA 16x16 accumulator

// async global->LDS, 16B per lane. LDS dest must be linear (base+lane*16);
// global src is per-lane (gather OK).
__device__ __forceinline__ void gload16(void* lds, const void* g) {
  __builtin_amdgcn_global_load_lds((const __attribute__((address_space(1))) char*)g,
                                   (__attribute__((address_space(3))) char*)lds, 16, 0, 0);
}

__device__ __forceinline__ ushort f2b(float f) {  // fp32 -> bf16 RNE bits
  union { float f; uint32_t u; } c; c.f = f;
  uint32_t u = c.u;
  return (ushort)((u + 0x7FFFu + ((u >> 16) & 1u)) >> 16);
}

// ---------------- cast fp32 -> bf16 (vectorized) ----------------
__global__ void cast_kernel(const float* __restrict__ in, ushort* __restrict__ out, int n4) {
  int i = blockIdx.x * blockDim.x + threadIdx.x;
  int stride = gridDim.x * blockDim.x;
  for (; i < n4; i += stride) {
    float4 v = ((const float4*)in)[i];
    ushort4 o;
    o.x = f2b(v.x); o.y = f2b(v.y); o.z = f2b(v.z); o.w = f2b(v.w);
    ((ushort4*)out)[i] = o;
  }
}

// ---------------- router: logits (fp64 accum), top-2, softmax, bucket counts ----------------
__global__ __launch_bounds__(256) void router_kernel(
    const float* __restrict__ x, const float* __restrict__ wg,
    float* __restrict__ logits_out, int4* __restrict__ recI, float2* __restrict__ recW,
    int* __restrict__ counts) {
  int wid = threadIdx.x >> 6, lane = threadIdx.x & 63;
  int tok = blockIdx.x * 4 + wid;
  if (tok >= T_TOK) return;
  const float4* xr = (const float4*)(x + (size_t)tok * HID);
  float4 xv[8];
#pragma unroll
  for (int j = 0; j < 8; ++j) xv[j] = xr[j * 64 + lane];
  float lf[NE];
#pragma unroll
  for (int e = 0; e < NE; ++e) {
    const float4* wrow = (const float4*)(wg + (size_t)e * HID);
    double acc = 0.0;
#pragma unroll
    for (int j = 0; j < 8; ++j) {
      float4 w4 = wrow[j * 64 + lane];
      acc += (double)xv[j].x * w4.x + (double)xv[j].y * w4.y +
             (double)xv[j].z * w4.z + (double)xv[j].w * w4.w;
    }
#pragma unroll
    for (int off = 32; off; off >>= 1) acc += __shfl_xor(acc, off);
    lf[e] = (float)acc;
  }
  if (lane == 0) {
#pragma unroll
    for (int e = 0; e < NE; ++e) logits_out[(size_t)tok * NE + e] = lf[e];
    int i1 = 0;
#pragma unroll
    for (int e = 1; e < NE; ++e) if (lf[e] > lf[i1]) i1 = e;   // lowest idx on tie
    int i2 = -1;
#pragma unroll
    for (int e = 0; e < NE; ++e) {
      if (e == i1) continue;
      if (i2 < 0 || lf[e] > lf[i2]) i2 = e;
    }
    float t = expf(lf[i2] - lf[i1]);          // <= 1
    float w1 = 1.0f / (1.0f + t);
    float w2 = t / (1.0f + t);
    int s1 = atomicAdd(&counts[i1], 1);
    int s2 = atomicAdd(&counts[i2], 1);
    recI[tok] = make_int4(i1, s1, i2, s2);
    recW[tok] = make_float2(w1, w2);
  }
}

__global__ void scan_kernel(const int* __restrict__ counts, int* __restrict__ offs) {
  int s = 0;
  for (int e = 0; e < NE; ++e) { offs[e] = s; s += counts[e]; }
  offs[NE] = s;
}

__global__ void scatter_kernel(const int4* __restrict__ recI, const float2* __restrict__ recW,
                               const int* __restrict__ offs,
                               int* __restrict__ tok_id, float* __restrict__ aw) {
  int t = blockIdx.x * blockDim.x + threadIdx.x;
  if (t >= T_TOK) return;
  int4 r = recI[t]; float2 w = recW[t];
  int p1 = offs[r.x] + r.y; tok_id[p1] = t; aw[p1] = w.x;
  int p2 = offs[r.z] + r.w; tok_id[p2] = t; aw[p2] = w.y;
}

// ---------------- GEMM1: gathered x @ w_fc_e^T, fused GLU, weight-scaled ----------------
// block: 128 gathered rows x 64 GLU cols (dual B tiles: cols j and j+1024 of w_fc)
// grid: 8 experts * 64 row-tiles * 16 col-tiles = 8192, early-exit beyond count.
__global__ __launch_bounds__(256, 2) void gemm1_kernel(
    const ushort* __restrict__ xb, const ushort* __restrict__ wfcb,
    const int* __restrict__ tok_id, const float* __restrict__ aw,
    const int* __restrict__ counts, const int* __restrict__ offs,
    ushort* __restrict__ hglu) {
  int bid = blockIdx.x;
  int e = bid >> 10;
  int rem = bid & 1023;
  int rt = rem >> 4;      // row tile 0..63
  int ct = rem & 15;      // GLU col tile 0..15 (64 cols each)
  int cnt = counts[e];
  if (rt * 128 >= cnt) return;
  int off = offs[e];
  int tid = threadIdx.x;

  __shared__ ushort As[2][128 * 32];
  __shared__ ushort Ba[2][64 * 32];
  __shared__ ushort Bb[2][64 * 32];

  // per-thread gathered tokens for the two A staging passes (rows fixed across K)
  int tokA[2];
#pragma unroll
  for (int p = 0; p < 2; ++p) {
    int row = (p * 256 + tid) >> 2;
    int slot = rt * 128 + row;
    tokA[p] = tok_id[off + (slot < cnt ? slot : cnt - 1)];
  }
  const size_t wbase_a = ((size_t)e * 2048 + (size_t)ct * 64) * HID;
  const size_t wbase_b = wbase_a + (size_t)1024 * HID;

  auto stage = [&](int b, int kt) {
    int k0 = kt * 32;
#pragma unroll
    for (int p = 0; p < 2; ++p) {
      int s = p * 256 + tid;
      gload16(&As[b][s * 8], xb + (size_t)tokA[p] * HID + k0 + (s & 3) * 8);
    }
    {
      int s = tid;
      size_t rk = (size_t)(s >> 2) * HID + k0 + (s & 3) * 8;
      gload16(&Ba[b][s * 8], wfcb + wbase_a + rk);
      gload16(&Bb[b][s * 8], wfcb + wbase_b + rk);
    }
  };

  int wid = tid >> 6, lane = tid & 63;
  int wr = wid >> 1, wc = wid & 1;      // 2x2 waves, each 64 rows x 32 cols (per half)
  int q = lane >> 4, r = lane & 15;

  f32x4 accA[4][2] = {};
  f32x4 accB[4][2] = {};

  stage(0, 0);
  __syncthreads();
  for (int kt = 0; kt < HID / 32; ++kt) {
    int cur = kt & 1;
    if (kt < HID / 32 - 1) stage(cur ^ 1, kt + 1);
    bf16x8 af[4], baf[2], bbf[2];
#pragma unroll
    for (int m = 0; m < 4; ++m)
      af[m] = *(const bf16x8*)&As[cur][(wr * 64 + m * 16 + r) * 32 + q * 8];
#pragma unroll
    for (int n = 0; n < 2; ++n) {
      baf[n] = *(const bf16x8*)&Ba[cur][(wc * 32 + n * 16 + r) * 32 + q * 8];
      bbf[n] = *(const bf16x8*)&Bb[cur][(wc * 32 + n * 16 + r) * 32 + q * 8];
    }
#pragma unroll
    for (int m = 0; m < 4; ++m)
#pragma unroll
      for (int n = 0; n < 2; ++n) {
        accA[m][n] = __builtin_amdgcn_mfma_f32_16x16x32_bf16(af[m], baf[n], accA[m][n], 0, 0, 0);
        accB[m][n] = __builtin_amdgcn_mfma_f32_16x16x32_bf16(af[m], bbf[n], accB[m][n], 0, 0, 0);
      }
    __syncthreads();
  }

  // epilogue: silu(a)*b * router_weight -> hglu[off+slot][ct*64 + ...]
#pragma unroll
  for (int m = 0; m < 4; ++m) {
    int rowbase = rt * 128 + wr * 64 + m * 16 + q * 4;
#pragma unroll
    for (int j = 0; j < 4; ++j) {
      int slot = rowbase + j;
      if (slot >= cnt) continue;
      float w = aw[off + slot];
      size_t rp = (size_t)(off + slot) * IM + ct * 64 + wc * 32 + r;
#pragma unroll
      for (int n = 0; n < 2; ++n) {
        float a = accA[m][n][j], b = accB[m][n][j];
        float g = (a / (1.0f + expf(-a))) * b * w;
        hglu[rp + n * 16] = f2b(g);
      }
    }
  }
}

// ---------------- GEMM2: hglu @ w_proj_e^T, atomicAdd into y ----------------
// block: 128 rows x 128 cols; grid 8*64*16=8192, early-exit.
__global__ __launch_bounds__(256, 2) void gemm2_kernel(
    const ushort* __restrict__ hglu, const ushort* __restrict__ wpb,
    const int* __restrict__ tok_id,
    const int* __restrict__ counts, const int* __restrict__ offs,
    float* __restrict__ y) {
  int bid = blockIdx.x;
  int e = bid >> 10;
  int rem = bid & 1023;
  int rt = rem >> 4;
  int ct = rem & 15;       // 16 col tiles of 128 over H=2048
  int cnt = counts[e];
  if (rt * 128 >= cnt) return;
  int off = offs[e];
  int tid = threadIdx.x;

  __shared__ ushort As[2][128 * 32];
  __shared__ ushort Bs[2][128 * 32];

  const size_t abase = (size_t)(off + rt * 128) * IM;
  const size_t bbase = ((size_t)e * 2048 + (size_t)ct * 128) * IM;

  auto stage = [&](int b, int kt) {
    int k0 = kt * 32;
#pragma unroll
    for (int p = 0; p < 2; ++p) {
      int s = p * 256 + tid;
      size_t rk = (size_t)(s >> 2) * IM + k0 + (s & 3) * 8;
      gload16(&As[b][s * 8], hglu + abase + rk);
      gload16(&Bs[b][s * 8], wpb + bbase + rk);
    }
  };

  int wid = tid >> 6, lane = tid & 63;
  int wr = wid >> 1, wc = wid & 1;      // each wave 64x64
  int q = lane >> 4, r = lane & 15;

  f32x4 acc[4][4] = {};

  stage(0, 0);
  __syncthreads();
  for (int kt = 0; kt < IM / 32; ++kt) {
    int cur = kt & 1;
    if (kt < IM / 32 - 1) stage(cur ^ 1, kt + 1);
    bf16x8 af[4], bf[4];
#pragma unroll
    for (int m = 0; m < 4; ++m)
      af[m] = *(const bf16x8*)&As[cur][(wr * 64 + m * 16 + r) * 32 + q * 8];
#pragma unroll
    for (int n = 0; n < 4; ++n)
      bf[n] = *(const bf16x8*)&Bs[cur][(wc * 64 + n * 16 + r) * 32 + q * 8];
#pragma unroll
    for (int m = 0; m < 4; ++m)
#pragma unroll
      for (int n = 0; n < 4; ++n)
        acc[m][n] = __builtin_amdgcn_mfma_f32_16x16x32_bf16(af[m], bf[n], acc[m][n], 0, 0, 0);
    __syncthreads();
  }

#pragma unroll
  for (int m = 0; m < 4; ++m) {
    int rowbase = rt * 128 + wr * 64 + m * 16 + q * 4;
#pragma unroll
    for (int j = 0; j < 4; ++j) {
      int slot = rowbase + j;
      if (slot >= cnt) continue;
      int tok = tok_id[off + slot];
      size_t yp = (size_t)tok * HID + ct * 128 + wc * 64 + r;
#pragma unroll
      for (int n = 0; n < 4; ++n)
        atomicAdd(&y[yp + n * 16], acc[m][n][j]);
    }
  }
}

// ---------------- launch ----------------
extern "C" void kernel_launch(void* const* d_in, const int* in_sizes, int n_in,
                              void* d_out, int out_size, void* d_ws, size_t ws_size,
                              hipStream_t stream) {
  const float* x     = (const float*)d_in[0];
  const float* wg    = (const float*)d_in[1];
  const float* wfc   = (const float*)d_in[2];
  const float* wproj = (const float*)d_in[3];
  float* y = (float*)d_out;
  float* logits = y + (size_t)T_TOK * HID;

  // workspace layout (bytes)
  char* ws = (char*)d_ws;
  ushort* xb   = (ushort*)(ws + 0);            // 33,554,432
  ushort* wfcb = (ushort*)(ws + 33554432);     // 67,108,864
  ushort* wpb  = (ushort*)(ws + 100663296);    // 33,554,432
  ushort* hglu = (ushort*)(ws + 134217728);    // (16384+128)*1024*2 = 33,816,576
  int*    tok  = (int*)   (ws + 168034304);    // 65,536
  float*  aw   = (float*) (ws + 168099840);    // 65,536
  int4*   recI = (int4*)  (ws + 168165376);    // 131,072
  float2* recW = (float2*)(ws + 168296448);    // 65,536
  int*  counts = (int*)   (ws + 168361984);    // 32
  int*  offs   = (int*)   (ws + 168362048);    // 36
  if (ws_size < 168362112) return;             // leave output poisoned -> clean failure

  hipMemsetAsync(y, 0, (size_t)T_TOK * HID * sizeof(float), stream);
  hipMemsetAsync(counts, 0, NE * sizeof(int), stream);

  cast_kernel<<<2048, 256, 0, stream>>>(x,     xb,   T_TOK * HID / 4);
  cast_kernel<<<4096, 256, 0, stream>>>(wfc,   wfcb, NE * 2 * IM * HID / 4);
  cast_kernel<<<2048, 256, 0, stream>>>(wproj, wpb,  NE * HID * IM / 4);

  router_kernel<<<T_TOK / 4, 256, 0, stream>>>(x, wg, logits, recI, recW, counts);
  scan_kernel<<<1, 1, 0, stream>>>(counts, offs);
  scatter_kernel<<<(T_TOK + 255) / 256, 256, 0, stream>>>(recI, recW, offs, tok, aw);

  gemm1_kernel<<<NE * 64 * 16, 256, 0, stream>>>(xb, wfcb, tok, aw, counts, offs, hglu);
  gemm2_kernel<<<NE * 64 * 16, 256, 0, stream>>>(hglu, wpb, tok, counts, offs, y);
}

// Round 2
// 857.127 us; speedup vs baseline: 1.0486x; 1.0486x over previous
//
#include <hip/hip_runtime.h>
#include <hip/hip_bf16.h>
#include <stdint.h>

// ---------------- problem constants ----------------
#define T_TOK 8192          // 4*2048 tokens
#define HID   2048          // hidden
#define IM    1024          // intermediate (GLU output)
#define NE    8             // experts

typedef __attribute__((ext_vector_type(8))) short bf16x8;   // 8 bf16 in 4 VGPRs
typedef __attribute__((ext_vector_type(4))) float f32x4;    // MFMA 16x16 accumulator

// async global->LDS, 16B per lane. LDS dest must be linear (base+lane*16);
// global src is per-lane (gather OK).
__device__ __forceinline__ void gload16(void* lds, const void* g) {
  __builtin_amdgcn_global_load_lds((const __attribute__((address_space(1))) char*)g,
                                   (__attribute__((address_space(3))) char*)lds, 16, 0, 0);
}

__device__ __forceinline__ ushort f2b(float f) {  // fp32 -> bf16 RNE bits
  union { float f; uint32_t u; } c; c.f = f;
  uint32_t u = c.u;
  return (ushort)((u + 0x7FFFu + ((u >> 16) & 1u)) >> 16);
}

// ---------------- cast fp32 -> bf16 (vectorized) ----------------
__global__ void cast_kernel(const float* __restrict__ in, ushort* __restrict__ out, int n4) {
  int i = blockIdx.x * blockDim.x + threadIdx.x;
  int stride = gridDim.x * blockDim.x;
  for (; i < n4; i += stride) {
    float4 v = ((const float4*)in)[i];
    ushort4 o;
    o.x = f2b(v.x); o.y = f2b(v.y); o.z = f2b(v.z); o.w = f2b(v.w);
    ((ushort4*)out)[i] = o;
  }
}

// ---------------- router: logits (fp64 accum), top-2, softmax ----------------
// Buckets are (expert, rank): bucket 2e   = primary assignments of expert e,
//                             bucket 2e+1 = secondary assignments of expert e.
__global__ __launch_bounds__(256) void router_kernel(
    const float* __restrict__ x, const float* __restrict__ wg,
    float* __restrict__ logits_out, int4* __restrict__ recI, float2* __restrict__ recW,
    int* __restrict__ counts2) {
  int wid = threadIdx.x >> 6, lane = threadIdx.x & 63;
  int tok = blockIdx.x * 4 + wid;
  if (tok >= T_TOK) return;
  const float4* xr = (const float4*)(x + (size_t)tok * HID);
  float4 xv[8];
#pragma unroll
  for (int j = 0; j < 8; ++j) xv[j] = xr[j * 64 + lane];
  float lf[NE];
#pragma unroll
  for (int e = 0; e < NE; ++e) {
    const float4* wrow = (const float4*)(wg + (size_t)e * HID);
    double acc = 0.0;
#pragma unroll
    for (int j = 0; j < 8; ++j) {
      float4 w4 = wrow[j * 64 + lane];
      acc += (double)xv[j].x * w4.x + (double)xv[j].y * w4.y +
             (double)xv[j].z * w4.z + (double)xv[j].w * w4.w;
    }
#pragma unroll
    for (int off = 32; off; off >>= 1) acc += __shfl_xor(acc, off);
    lf[e] = (float)acc;
  }
  if (lane == 0) {
#pragma unroll
    for (int e = 0; e < NE; ++e) logits_out[(size_t)tok * NE + e] = lf[e];
    int i1 = 0;
#pragma unroll
    for (int e = 1; e < NE; ++e) if (lf[e] > lf[i1]) i1 = e;   // lowest idx on tie
    int i2 = -1;
#pragma unroll
    for (int e = 0; e < NE; ++e) {
      if (e == i1) continue;
      if (i2 < 0 || lf[e] > lf[i2]) i2 = e;
    }
    float t = expf(lf[i2] - lf[i1]);          // <= 1
    float w1 = 1.0f / (1.0f + t);
    float w2 = t / (1.0f + t);
    int s1 = atomicAdd(&counts2[i1 * 2 + 0], 1);
    int s2 = atomicAdd(&counts2[i2 * 2 + 1], 1);
    recI[tok] = make_int4(i1, s1, i2, s2);
    recW[tok] = make_float2(w1, w2);
  }
}

// offs2[b] = exclusive scan of the 16 (expert,rank) buckets;
// ecnt/eoff = per-expert combined (primary+secondary) ranges for gemm1.
__global__ void scan_kernel(const int* __restrict__ counts2, int* __restrict__ offs2,
                            int* __restrict__ ecnt, int* __restrict__ eoff) {
  int s = 0;
  for (int b = 0; b < 2 * NE; ++b) { offs2[b] = s; s += counts2[b]; }
  offs2[2 * NE] = s;
  for (int e = 0; e < NE; ++e) {
    eoff[e] = offs2[2 * e];
    ecnt[e] = counts2[2 * e] + counts2[2 * e + 1];
  }
}

__global__ void scatter_kernel(const int4* __restrict__ recI, const float2* __restrict__ recW,
                               const int* __restrict__ offs2,
                               int* __restrict__ tok_id, float* __restrict__ aw) {
  int t = blockIdx.x * blockDim.x + threadIdx.x;
  if (t >= T_TOK) return;
  int4 r = recI[t]; float2 w = recW[t];
  int p1 = offs2[r.x * 2 + 0] + r.y; tok_id[p1] = t; aw[p1] = w.x;
  int p2 = offs2[r.z * 2 + 1] + r.w; tok_id[p2] = t; aw[p2] = w.y;
}

// ---------------- GEMM1: gathered x @ w_fc_e^T, fused GLU, weight-scaled ----------------
// block: 128 gathered rows x 64 GLU cols (dual B tiles: cols j and j+1024 of w_fc)
// grid: 8 experts * 64 row-tiles * 16 col-tiles = 8192, early-exit beyond count.
__global__ __launch_bounds__(256, 2) void gemm1_kernel(
    const ushort* __restrict__ xb, const ushort* __restrict__ wfcb,
    const int* __restrict__ tok_id, const float* __restrict__ aw,
    const int* __restrict__ ecnt, const int* __restrict__ eoff,
    ushort* __restrict__ hglu) {
  int bid = blockIdx.x;
  int e = bid >> 10;
  int rem = bid & 1023;
  int rt = rem >> 4;      // row tile 0..63
  int ct = rem & 15;      // GLU col tile 0..15 (64 cols each)
  int cnt = ecnt[e];
  if (cnt == 0 || rt * 128 >= cnt) return;
  int off = eoff[e];
  int tid = threadIdx.x;

  __shared__ ushort As[2][128 * 32];
  __shared__ ushort Ba[2][64 * 32];
  __shared__ ushort Bb[2][64 * 32];

  // per-thread gathered tokens for the two A staging passes (rows fixed across K)
  int tokA[2];
#pragma unroll
  for (int p = 0; p < 2; ++p) {
    int row = (p * 256 + tid) >> 2;
    int slot = rt * 128 + row;
    tokA[p] = tok_id[off + (slot < cnt ? slot : cnt - 1)];
  }
  const size_t wbase_a = ((size_t)e * 2048 + (size_t)ct * 64) * HID;
  const size_t wbase_b = wbase_a + (size_t)1024 * HID;

  auto stage = [&](int b, int kt) {
    int k0 = kt * 32;
#pragma unroll
    for (int p = 0; p < 2; ++p) {
      int s = p * 256 + tid;
      gload16(&As[b][s * 8], xb + (size_t)tokA[p] * HID + k0 + (s & 3) * 8);
    }
    {
      int s = tid;
      size_t rk = (size_t)(s >> 2) * HID + k0 + (s & 3) * 8;
      gload16(&Ba[b][s * 8], wfcb + wbase_a + rk);
      gload16(&Bb[b][s * 8], wfcb + wbase_b + rk);
    }
  };

  int wid = tid >> 6, lane = tid & 63;
  int wr = wid >> 1, wc = wid & 1;      // 2x2 waves, each 64 rows x 32 cols (per half)
  int q = lane >> 4, r = lane & 15;

  f32x4 accA[4][2] = {};
  f32x4 accB[4][2] = {};

  stage(0, 0);
  __syncthreads();
  for (int kt = 0; kt < HID / 32; ++kt) {
    int cur = kt & 1;
    if (kt < HID / 32 - 1) stage(cur ^ 1, kt + 1);
    bf16x8 af[4], baf[2], bbf[2];
#pragma unroll
    for (int m = 0; m < 4; ++m)
      af[m] = *(const bf16x8*)&As[cur][(wr * 64 + m * 16 + r) * 32 + q * 8];
#pragma unroll
    for (int n = 0; n < 2; ++n) {
      baf[n] = *(const bf16x8*)&Ba[cur][(wc * 32 + n * 16 + r) * 32 + q * 8];
      bbf[n] = *(const bf16x8*)&Bb[cur][(wc * 32 + n * 16 + r) * 32 + q * 8];
    }
#pragma unroll
    for (int m = 0; m < 4; ++m)
#pragma unroll
      for (int n = 0; n < 2; ++n) {
        accA[m][n] = __builtin_amdgcn_mfma_f32_16x16x32_bf16(af[m], baf[n], accA[m][n], 0, 0, 0);
        accB[m][n] = __builtin_amdgcn_mfma_f32_16x16x32_bf16(af[m], bbf[n], accB[m][n], 0, 0, 0);
      }
    __syncthreads();
  }

  // epilogue: silu(a)*b * router_weight -> hglu[off+slot][ct*64 + ...]
#pragma unroll
  for (int m = 0; m < 4; ++m) {
    int rowbase = rt * 128 + wr * 64 + m * 16 + q * 4;
#pragma unroll
    for (int j = 0; j < 4; ++j) {
      int slot = rowbase + j;
      if (slot >= cnt) continue;
      float w = aw[off + slot];
      size_t rp = (size_t)(off + slot) * IM + ct * 64 + wc * 32 + r;
#pragma unroll
      for (int n = 0; n < 2; ++n) {
        float a = accA[m][n][j], b = accB[m][n][j];
        float g = (a / (1.0f + expf(-a))) * b * w;
        hglu[rp + n * 16] = f2b(g);
      }
    }
  }
}

// ---------------- GEMM2: hglu @ w_proj_e^T, store (pass 0) / non-atomic add (pass 1) ----------------
// Bucket (2e+pass) rows are disjoint token sets within a pass; pass 0 covers every
// token exactly once (=> plain store, no memset), pass 1 adds exactly once.
__global__ __launch_bounds__(256, 2) void gemm2_kernel(
    const ushort* __restrict__ hglu, const ushort* __restrict__ wpb,
    const int* __restrict__ tok_id,
    const int* __restrict__ counts2, const int* __restrict__ offs2,
    float* __restrict__ y, int pass) {
  int bid = blockIdx.x;
  int e = bid >> 10;
  int rem = bid & 1023;
  int rt = rem >> 4;
  int ct = rem & 15;       // 16 col tiles of 128 over H=2048
  int cnt = counts2[2 * e + pass];
  if (cnt == 0 || rt * 128 >= cnt) return;
  int off = offs2[2 * e + pass];
  int tid = threadIdx.x;

  __shared__ ushort As[2][128 * 32];
  __shared__ ushort Bs[2][128 * 32];

  const size_t abase = (size_t)(off + rt * 128) * IM;
  const size_t bbase = ((size_t)e * 2048 + (size_t)ct * 128) * IM;

  auto stage = [&](int b, int kt) {
    int k0 = kt * 32;
#pragma unroll
    for (int p = 0; p < 2; ++p) {
      int s = p * 256 + tid;
      size_t rk = (size_t)(s >> 2) * IM + k0 + (s & 3) * 8;
      gload16(&As[b][s * 8], hglu + abase + rk);
      gload16(&Bs[b][s * 8], wpb + bbase + rk);
    }
  };

  int wid = tid >> 6, lane = tid & 63;
  int wr = wid >> 1, wc = wid & 1;      // each wave 64x64
  int q = lane >> 4, r = lane & 15;

  f32x4 acc[4][4] = {};

  stage(0, 0);
  __syncthreads();
  for (int kt = 0; kt < IM / 32; ++kt) {
    int cur = kt & 1;
    if (kt < IM / 32 - 1) stage(cur ^ 1, kt + 1);
    bf16x8 af[4], bf[4];
#pragma unroll
    for (int m = 0; m < 4; ++m)
      af[m] = *(const bf16x8*)&As[cur][(wr * 64 + m * 16 + r) * 32 + q * 8];
#pragma unroll
    for (int n = 0; n < 4; ++n)
      bf[n] = *(const bf16x8*)&Bs[cur][(wc * 64 + n * 16 + r) * 32 + q * 8];
#pragma unroll
    for (int m = 0; m < 4; ++m)
#pragma unroll
      for (int n = 0; n < 4; ++n)
        acc[m][n] = __builtin_amdgcn_mfma_f32_16x16x32_bf16(af[m], bf[n], acc[m][n], 0, 0, 0);
    __syncthreads();
  }

#pragma unroll
  for (int m = 0; m < 4; ++m) {
    int rowbase = rt * 128 + wr * 64 + m * 16 + q * 4;
#pragma unroll
    for (int j = 0; j < 4; ++j) {
      int slot = rowbase + j;
      if (slot >= cnt) continue;
      int tok = tok_id[off + slot];
      float* yp = &y[(size_t)tok * HID + ct * 128 + wc * 64 + r];
      if (pass == 0) {
#pragma unroll
        for (int n = 0; n < 4; ++n) yp[n * 16] = acc[m][n][j];
      } else {
#pragma unroll
        for (int n = 0; n < 4; ++n) yp[n * 16] += acc[m][n][j];
      }
    }
  }
}

// ---------------- launch ----------------
extern "C" void kernel_launch(void* const* d_in, const int* in_sizes, int n_in,
                              void* d_out, int out_size, void* d_ws, size_t ws_size,
                              hipStream_t stream) {
  const float* x     = (const float*)d_in[0];
  const float* wg    = (const float*)d_in[1];
  const float* wfc   = (const float*)d_in[2];
  const float* wproj = (const float*)d_in[3];
  float* y = (float*)d_out;
  float* logits = y + (size_t)T_TOK * HID;

  // workspace layout (bytes)
  char* ws = (char*)d_ws;
  ushort* xb    = (ushort*)(ws + 0);            // 33,554,432
  ushort* wfcb  = (ushort*)(ws + 33554432);     // 67,108,864
  ushort* wpb   = (ushort*)(ws + 100663296);    // 33,554,432
  ushort* hglu  = (ushort*)(ws + 134217728);    // (16384+128)*1024*2 = 33,816,576
  int*    tok   = (int*)   (ws + 168034304);    // 65,536
  float*  aw    = (float*) (ws + 168099840);    // 65,536
  int4*   recI  = (int4*)  (ws + 168165376);    // 131,072
  float2* recW  = (float2*)(ws + 168296448);    // 65,536
  int* counts2  = (int*)   (ws + 168361984);    // 16 ints
  int* offs2    = (int*)   (ws + 168362048);    // 17 ints
  int* ecnt     = (int*)   (ws + 168362120);    // 8 ints
  int* eoff     = (int*)   (ws + 168362152);    // 8 ints
  if (ws_size < 168362184) return;              // leave output poisoned -> clean failure

  hipMemsetAsync(counts2, 0, 2 * NE * sizeof(int), stream);

  cast_kernel<<<2048, 256, 0, stream>>>(x,     xb,   T_TOK * HID / 4);
  cast_kernel<<<4096, 256, 0, stream>>>(wfc,   wfcb, NE * 2 * IM * HID / 4);
  cast_kernel<<<2048, 256, 0, stream>>>(wproj, wpb,  NE * HID * IM / 4);

  router_kernel<<<T_TOK / 4, 256, 0, stream>>>(x, wg, logits, recI, recW, counts2);
  scan_kernel<<<1, 1, 0, stream>>>(counts2, offs2, ecnt, eoff);
  scatter_kernel<<<(T_TOK + 255) / 256, 256, 0, stream>>>(recI, recW, offs2, tok, aw);

  gemm1_kernel<<<NE * 64 * 16, 256, 0, stream>>>(xb, wfcb, tok, aw, ecnt, eoff, hglu);
  gemm2_kernel<<<NE * 64 * 16, 256, 0, stream>>>(hglu, wpb, tok, counts2, offs2, y, 0);
  gemm2_kernel<<<NE * 64 * 16, 256, 0, stream>>>(hglu, wpb, tok, counts2, offs2, y, 1);
}

// Round 5
// 844.461 us; speedup vs baseline: 1.0643x; 1.0150x over previous
//
#include <hip/hip_runtime.h>
#include <hip/hip_bf16.h>
#include <stdint.h>

// ---------------- problem constants ----------------
#define T_TOK 8192          // 4*2048 tokens
#define HID   2048          // hidden
#define IM    1024          // intermediate (GLU output)
#define NE    8             // experts

typedef __attribute__((ext_vector_type(8))) short bf16x8;   // 8 bf16 in 4 VGPRs
typedef __attribute__((ext_vector_type(4))) float f32x4;    // MFMA 16x16 accumulator

// async global->LDS, 16B per lane. LDS dest must be linear (base+lane*16);
// global src is per-lane (gather / pre-swizzle OK).
__device__ __forceinline__ void gload16(void* lds, const void* g) {
  __builtin_amdgcn_global_load_lds((const __attribute__((address_space(1))) char*)g,
                                   (__attribute__((address_space(3))) char*)lds, 16, 0, 0);
}

__device__ __forceinline__ ushort f2b(float f) {  // fp32 -> bf16 RNE bits
  union { float f; uint32_t u; } c; c.f = f;
  uint32_t u = c.u;
  return (ushort)((u + 0x7FFFu + ((u >> 16) & 1u)) >> 16);
}

#define MFMA16(a, b, c) __builtin_amdgcn_mfma_f32_16x16x32_bf16((a), (b), (c), 0, 0, 0)

// ---------------- cast fp32 -> bf16 for weights (merged) ----------------
__global__ void cast_w_kernel(const float* __restrict__ wfc, const float* __restrict__ wproj,
                              ushort* __restrict__ wfcb, ushort* __restrict__ wpb) {
  const int NFC4 = NE * 2 * IM * HID / 4;   // 8,388,608
  const int NPJ4 = NE * HID * IM / 4;       // 4,194,304
  int i = blockIdx.x * blockDim.x + threadIdx.x;
  int stride = gridDim.x * blockDim.x;
  for (; i < NFC4 + NPJ4; i += stride) {
    const float4* s; ushort4* d; int k;
    if (i < NFC4) { s = (const float4*)wfc;   d = (ushort4*)wfcb; k = i; }
    else          { s = (const float4*)wproj; d = (ushort4*)wpb;  k = i - NFC4; }
    float4 v = s[k];
    ushort4 o;
    o.x = f2b(v.x); o.y = f2b(v.y); o.z = f2b(v.z); o.w = f2b(v.w);
    d[k] = o;
  }
}

// ---------------- router: logits (fp64 accum), top-2, softmax; also emits xb ----------------
// Buckets are (expert, rank): bucket 2e = primary, bucket 2e+1 = secondary.
__global__ __launch_bounds__(256) void router_kernel(
    const float* __restrict__ x, const float* __restrict__ wg,
    float* __restrict__ logits_out, ushort* __restrict__ xb,
    int4* __restrict__ recI, float2* __restrict__ recW,
    int* __restrict__ counts2) {
  int wid = threadIdx.x >> 6, lane = threadIdx.x & 63;
  int tok = blockIdx.x * 4 + wid;
  if (tok >= T_TOK) return;
  const float4* xr = (const float4*)(x + (size_t)tok * HID);
  float4 xv[8];
#pragma unroll
  for (int j = 0; j < 8; ++j) xv[j] = xr[j * 64 + lane];
  // emit bf16 x row (saves a separate 67MB-read cast pass)
  ushort4* xbr = (ushort4*)(xb + (size_t)tok * HID);
#pragma unroll
  for (int j = 0; j < 8; ++j) {
    ushort4 o;
    o.x = f2b(xv[j].x); o.y = f2b(xv[j].y); o.z = f2b(xv[j].z); o.w = f2b(xv[j].w);
    xbr[j * 64 + lane] = o;
  }
  float lf[NE];
#pragma unroll
  for (int e = 0; e < NE; ++e) {
    const float4* wrow = (const float4*)(wg + (size_t)e * HID);
    double acc = 0.0;
#pragma unroll
    for (int j = 0; j < 8; ++j) {
      float4 w4 = wrow[j * 64 + lane];
      acc += (double)xv[j].x * w4.x + (double)xv[j].y * w4.y +
             (double)xv[j].z * w4.z + (double)xv[j].w * w4.w;
    }
#pragma unroll
    for (int off = 32; off; off >>= 1) acc += __shfl_xor(acc, off);
    lf[e] = (float)acc;
  }
  if (lane == 0) {
#pragma unroll
    for (int e = 0; e < NE; ++e) logits_out[(size_t)tok * NE + e] = lf[e];
    int i1 = 0;
#pragma unroll
    for (int e = 1; e < NE; ++e) if (lf[e] > lf[i1]) i1 = e;   // lowest idx on tie
    int i2 = -1;
#pragma unroll
    for (int e = 0; e < NE; ++e) {
      if (e == i1) continue;
      if (i2 < 0 || lf[e] > lf[i2]) i2 = e;
    }
    float t = expf(lf[i2] - lf[i1]);          // <= 1
    float w1 = 1.0f / (1.0f + t);
    float w2 = t / (1.0f + t);
    int s1 = atomicAdd(&counts2[i1 * 2 + 0], 1);
    int s2 = atomicAdd(&counts2[i2 * 2 + 1], 1);
    recI[tok] = make_int4(i1, s1, i2, s2);
    recW[tok] = make_float2(w1, w2);
  }
}

__global__ void scan_kernel(const int* __restrict__ counts2, int* __restrict__ offs2,
                            int* __restrict__ ecnt, int* __restrict__ eoff) {
  int s = 0;
  for (int b = 0; b < 2 * NE; ++b) { offs2[b] = s; s += counts2[b]; }
  offs2[2 * NE] = s;
  for (int e = 0; e < NE; ++e) {
    eoff[e] = offs2[2 * e];
    ecnt[e] = counts2[2 * e] + counts2[2 * e + 1];
  }
}

__global__ void scatter_kernel(const int4* __restrict__ recI, const float2* __restrict__ recW,
                               const int* __restrict__ offs2,
                               int* __restrict__ tok_id, float* __restrict__ aw) {
  int t = blockIdx.x * blockDim.x + threadIdx.x;
  if (t >= T_TOK) return;
  int4 r = recI[t]; float2 w = recW[t];
  int p1 = offs2[r.x * 2 + 0] + r.y; tok_id[p1] = t; aw[p1] = w.x;
  int p2 = offs2[r.z * 2 + 1] + r.w; tok_id[p2] = t; aw[p2] = w.y;
}

// T2 swizzle: LDS row stride is 64B; reads of a column-16B-slice across rows are
// 8-way bank conflicts. Swizzled 16B-slot index gq = q ^ ((row>>1)&3) spreads 16
// consecutive rows over 8 banks (2-way = free). Write side pre-swizzles the
// GLOBAL source (gload_lds dest must stay linear); read side applies same XOR.

// ---------------- GEMM1: gathered x @ w_fc_e^T, fused GLU ----------------
// 256 rows x 128 GLU cols (256 fc cols), 512 thr / 8 waves (2Mx4N), BK=32,
// 4-deep LDS ring, counted vmcnt(8), per-phase barriers + setprio.
__global__ __launch_bounds__(512, 2) void gemm1_kernel(
    const ushort* __restrict__ xb, const ushort* __restrict__ wfcb,
    const int* __restrict__ tok_id, const float* __restrict__ aw,
    const int* __restrict__ ecnt, const int* __restrict__ eoff,
    ushort* __restrict__ hglu) {
  int bid = blockIdx.x;
  int e = bid >> 9;           // 8 experts
  int rt = (bid >> 3) & 63;   // up to 64 row tiles of 256 (worst-case cnt=16384)
  int ct = bid & 7;           // 8 GLU col tiles of 128
  int cnt = ecnt[e];
  if (cnt == 0 || rt * 256 >= cnt) return;
  int off = eoff[e];
  int tid = threadIdx.x;

  __shared__ ushort lds[4][512 * 32];   // 128 KiB: ring of 4 K-tiles (A 256 | Ba 128 | Bb 128)

  // staging setup: 4 gload16 per thread per K-tile
  int sslot[4]; const ushort* gsrc[4];
#pragma unroll
  for (int l = 0; l < 4; ++l) {
    int s = l * 512 + tid;
    int lrow = s >> 2, qs = s & 3;
    int gq = qs ^ ((lrow >> 1) & 3);          // pre-swizzled global 16B-slot
    sslot[l] = s * 8;
    if (l < 2) {                               // A rows 0..255 (gathered tokens)
      int slotr = rt * 256 + lrow;
      if (slotr >= cnt) slotr = cnt - 1;
      gsrc[l] = xb + (size_t)tok_id[off + slotr] * HID + gq * 8;
    } else if (l == 2) {                       // Ba rows 256..383 -> fc cols ct*128..+127
      int fcr = e * 2048 + ct * 128 + (lrow - 256);
      gsrc[l] = wfcb + (size_t)fcr * HID + gq * 8;
    } else {                                   // Bb rows 384..511 -> fc cols +1024
      int fcr = e * 2048 + 1024 + ct * 128 + (lrow - 384);
      gsrc[l] = wfcb + (size_t)fcr * HID + gq * 8;
    }
  }

  int wid = tid >> 6, lane = tid & 63;
  int wr = wid >> 2, wc = wid & 3;            // wave tile: 128 rows x 32 GLU cols
  int q = lane >> 4, r = lane & 15;

  int offA[8], offBa[2], offBb[2];            // swizzled ds_read offsets (ushort units)
#pragma unroll
  for (int m = 0; m < 8; ++m) {
    int lrow = wr * 128 + m * 16 + r;
    offA[m] = lrow * 32 + ((q ^ ((lrow >> 1) & 3)) << 3);
  }
#pragma unroll
  for (int n = 0; n < 2; ++n) {
    int lr1 = 256 + wc * 32 + n * 16 + r;
    offBa[n] = lr1 * 32 + ((q ^ ((lr1 >> 1) & 3)) << 3);
    int lr2 = 384 + wc * 32 + n * 16 + r;
    offBb[n] = lr2 * 32 + ((q ^ ((lr2 >> 1) & 3)) << 3);
  }

  f32x4 accA[8][2] = {}; f32x4 accB[8][2] = {};
  const int NT = HID / 32;   // 64

#define G1_STAGE(bufi, t, l) gload16(&lds[bufi][sslot[l]], gsrc[l] + (size_t)(t) * 32)
  // prologue: tiles 0..2 in flight; wait tile 0 (8 = tiles 1,2 outstanding)
#pragma unroll
  for (int t = 0; t < 3; ++t) {
    G1_STAGE(t, t, 0); G1_STAGE(t, t, 1); G1_STAGE(t, t, 2); G1_STAGE(t, t, 3);
  }
  asm volatile("s_waitcnt vmcnt(8)" ::: "memory");
  __builtin_amdgcn_s_barrier();

  for (int t = 0; t < NT; ++t) {
    int cur = t & 3;
    const ushort* Bv = &lds[cur][0];
    int nb = (t + 3) & 3;
    bool pf = (t + 3) < NT;
    // B frags live across both phases
    bf16x8 ba0 = *(const bf16x8*)&Bv[offBa[0]];
    bf16x8 ba1 = *(const bf16x8*)&Bv[offBa[1]];
    bf16x8 bb0 = *(const bf16x8*)&Bv[offBb[0]];
    bf16x8 bb1 = *(const bf16x8*)&Bv[offBb[1]];
    // ---- phase 0: m 0..3 ----
    bf16x8 af[4];
#pragma unroll
    for (int m = 0; m < 4; ++m) af[m] = *(const bf16x8*)&Bv[offA[m]];
    if (pf) { G1_STAGE(nb, t + 3, 0); G1_STAGE(nb, t + 3, 1); }
    __builtin_amdgcn_s_barrier();
    __builtin_amdgcn_s_setprio(1);
#pragma unroll
    for (int m = 0; m < 4; ++m) {
      accA[m][0] = MFMA16(af[m], ba0, accA[m][0]);
      accA[m][1] = MFMA16(af[m], ba1, accA[m][1]);
      accB[m][0] = MFMA16(af[m], bb0, accB[m][0]);
      accB[m][1] = MFMA16(af[m], bb1, accB[m][1]);
    }
    __builtin_amdgcn_s_setprio(0);
    __builtin_amdgcn_s_barrier();
    // ---- phase 1: m 4..7 ----
#pragma unroll
    for (int m = 0; m < 4; ++m) af[m] = *(const bf16x8*)&Bv[offA[4 + m]];
    if (pf) { G1_STAGE(nb, t + 3, 2); G1_STAGE(nb, t + 3, 3); }
    __builtin_amdgcn_s_barrier();
    __builtin_amdgcn_s_setprio(1);
#pragma unroll
    for (int m = 0; m < 4; ++m) {
      accA[4 + m][0] = MFMA16(af[m], ba0, accA[4 + m][0]);
      accA[4 + m][1] = MFMA16(af[m], ba1, accA[4 + m][1]);
      accB[4 + m][0] = MFMA16(af[m], bb0, accB[4 + m][0]);
      accB[4 + m][1] = MFMA16(af[m], bb1, accB[4 + m][1]);
    }
    __builtin_amdgcn_s_setprio(0);
    // ---- iteration end: counted wait (next tile ready), never 0 mid-loop ----
    if (t < NT - 1) {
      if (t + 3 < NT)      asm volatile("s_waitcnt vmcnt(8)" ::: "memory");
      else if (t + 2 < NT) asm volatile("s_waitcnt vmcnt(4)" ::: "memory");
      else                 asm volatile("s_waitcnt vmcnt(0)" ::: "memory");
      __builtin_amdgcn_s_barrier();
    }
  }

  // epilogue: silu(a)*b * router_weight -> hglu
#pragma unroll
  for (int m = 0; m < 8; ++m) {
#pragma unroll
    for (int j = 0; j < 4; ++j) {
      int slot = rt * 256 + wr * 128 + m * 16 + q * 4 + j;
      if (slot >= cnt) continue;
      float w = aw[off + slot];
      size_t rp = (size_t)(off + slot) * IM + ct * 128 + wc * 32 + r;
#pragma unroll
      for (int n = 0; n < 2; ++n) {
        float a = accA[m][n][j], b = accB[m][n][j];
        float g = (a / (1.0f + expf(-a))) * b * w;
        hglu[rp + n * 16] = f2b(g);
      }
    }
  }
}

// ---------------- GEMM2: hglu @ w_proj_e^T -> y (pass0 store, pass1 add) ----------------
// 256 rows x 256 cols, same 8-phase-counted structure, K=1024 (NT=32).
__global__ __launch_bounds__(512, 2) void gemm2_kernel(
    const ushort* __restrict__ hglu, const ushort* __restrict__ wpb,
    const int* __restrict__ tok_id,
    const int* __restrict__ counts2, const int* __restrict__ offs2,
    float* __restrict__ y, int pass) {
  int bid = blockIdx.x;
  int e = bid >> 8;           // 8 experts
  int rt = (bid >> 3) & 31;   // up to 32 row tiles of 256 (worst-case cnt=8192)
  int ct = bid & 7;           // 8 col tiles of 256 over H=2048
  int cnt = counts2[2 * e + pass];
  if (cnt == 0 || rt * 256 >= cnt) return;
  int off = offs2[2 * e + pass];
  int tid = threadIdx.x;

  __shared__ ushort lds[4][512 * 32];   // ring of 4 K-tiles (A 256 | B 256)

  int sslot[4]; const ushort* gsrc[4];
#pragma unroll
  for (int l = 0; l < 4; ++l) {
    int s = l * 512 + tid;
    int lrow = s >> 2, qs = s & 3;
    int gq = qs ^ ((lrow >> 1) & 3);
    sslot[l] = s * 8;
    if (l < 2) {                               // A rows: hglu (padded; epilogue guards)
      size_t arow = (size_t)(off + rt * 256 + lrow);
      gsrc[l] = hglu + arow * IM + gq * 8;
    } else {                                   // B rows 256..511 -> y-cols ct*256..+255
      int wrow = e * 2048 + ct * 256 + (lrow - 256);
      gsrc[l] = wpb + (size_t)wrow * IM + gq * 8;
    }
  }

  int wid = tid >> 6, lane = tid & 63;
  int wr = wid >> 2, wc = wid & 3;            // wave tile: 128 rows x 64 cols
  int q = lane >> 4, r = lane & 15;

  int offA[8], offB[4];
#pragma unroll
  for (int m = 0; m < 8; ++m) {
    int lrow = wr * 128 + m * 16 + r;
    offA[m] = lrow * 32 + ((q ^ ((lrow >> 1) & 3)) << 3);
  }
#pragma unroll
  for (int n = 0; n < 4; ++n) {
    int lrow = 256 + wc * 64 + n * 16 + r;
    offB[n] = lrow * 32 + ((q ^ ((lrow >> 1) & 3)) << 3);
  }

  f32x4 acc[8][4] = {};
  const int NT = IM / 32;   // 32

#define G2_STAGE(bufi, t, l) gload16(&lds[bufi][sslot[l]], gsrc[l] + (size_t)(t) * 32)
#pragma unroll
  for (int t = 0; t < 3; ++t) {
    G2_STAGE(t, t, 0); G2_STAGE(t, t, 1); G2_STAGE(t, t, 2); G2_STAGE(t, t, 3);
  }
  asm volatile("s_waitcnt vmcnt(8)" ::: "memory");
  __builtin_amdgcn_s_barrier();

  for (int t = 0; t < NT; ++t) {
    int cur = t & 3;
    const ushort* Bv = &lds[cur][0];
    int nb = (t + 3) & 3;
    bool pf = (t + 3) < NT;
    bf16x8 bf0 = *(const bf16x8*)&Bv[offB[0]];
    bf16x8 bf1 = *(const bf16x8*)&Bv[offB[1]];
    bf16x8 bf2 = *(const bf16x8*)&Bv[offB[2]];
    bf16x8 bf3 = *(const bf16x8*)&Bv[offB[3]];
    // ---- phase 0: m 0..3 ----
    bf16x8 af[4];
#pragma unroll
    for (int m = 0; m < 4; ++m) af[m] = *(const bf16x8*)&Bv[offA[m]];
    if (pf) { G2_STAGE(nb, t + 3, 0); G2_STAGE(nb, t + 3, 1); }
    __builtin_amdgcn_s_barrier();
    __builtin_amdgcn_s_setprio(1);
#pragma unroll
    for (int m = 0; m < 4; ++m) {
      acc[m][0] = MFMA16(af[m], bf0, acc[m][0]);
      acc[m][1] = MFMA16(af[m], bf1, acc[m][1]);
      acc[m][2] = MFMA16(af[m], bf2, acc[m][2]);
      acc[m][3] = MFMA16(af[m], bf3, acc[m][3]);
    }
    __builtin_amdgcn_s_setprio(0);
    __builtin_amdgcn_s_barrier();
    // ---- phase 1: m 4..7 ----
#pragma unroll
    for (int m = 0; m < 4; ++m) af[m] = *(const bf16x8*)&Bv[offA[4 + m]];
    if (pf) { G2_STAGE(nb, t + 3, 2); G2_STAGE(nb, t + 3, 3); }
    __builtin_amdgcn_s_barrier();
    __builtin_amdgcn_s_setprio(1);
#pragma unroll
    for (int m = 0; m < 4; ++m) {
      acc[4 + m][0] = MFMA16(af[m], bf0, acc[4 + m][0]);
      acc[4 + m][1] = MFMA16(af[m], bf1, acc[4 + m][1]);
      acc[4 + m][2] = MFMA16(af[m], bf2, acc[4 + m][2]);
      acc[4 + m][3] = MFMA16(af[m], bf3, acc[4 + m][3]);
    }
    __builtin_amdgcn_s_setprio(0);
    if (t < NT - 1) {
      if (t + 3 < NT)      asm volatile("s_waitcnt vmcnt(8)" ::: "memory");
      else if (t + 2 < NT) asm volatile("s_waitcnt vmcnt(4)" ::: "memory");
      else                 asm volatile("s_waitcnt vmcnt(0)" ::: "memory");
      __builtin_amdgcn_s_barrier();
    }
  }

#pragma unroll
  for (int m = 0; m < 8; ++m) {
#pragma unroll
    for (int j = 0; j < 4; ++j) {
      int slot = rt * 256 + wr * 128 + m * 16 + q * 4 + j;
      if (slot >= cnt) continue;
      int tok = tok_id[off + slot];
      float* yp = &y[(size_t)tok * HID + ct * 256 + wc * 64 + r];
      if (pass == 0) {
#pragma unroll
        for (int n = 0; n < 4; ++n) yp[n * 16] = acc[m][n][j];
      } else {
#pragma unroll
        for (int n = 0; n < 4; ++n) yp[n * 16] += acc[m][n][j];
      }
    }
  }
}

// ---------------- launch ----------------
extern "C" void kernel_launch(void* const* d_in, const int* in_sizes, int n_in,
                              void* d_out, int out_size, void* d_ws, size_t ws_size,
                              hipStream_t stream) {
  const float* x     = (const float*)d_in[0];
  const float* wg    = (const float*)d_in[1];
  const float* wfc   = (const float*)d_in[2];
  const float* wproj = (const float*)d_in[3];
  float* y = (float*)d_out;
  float* logits = y + (size_t)T_TOK * HID;

  // workspace layout (bytes)
  char* ws = (char*)d_ws;
  ushort* xb    = (ushort*)(ws + 0);            // 33,554,432
  ushort* wfcb  = (ushort*)(ws + 33554432);     // 67,108,864
  ushort* wpb   = (ushort*)(ws + 100663296);    // 33,554,432
  ushort* hglu  = (ushort*)(ws + 134217728);    // (16384+256)*1024*2 = 34,078,720
  int*    tok   = (int*)   (ws + 168296448);    // 65,536
  float*  aw    = (float*) (ws + 168361984);    // 65,536
  int4*   recI  = (int4*)  (ws + 168427520);    // 131,072
  float2* recW  = (float2*)(ws + 168558592);    // 65,536
  int* counts2  = (int*)   (ws + 168624128);    // 16 ints
  int* offs2    = (int*)   (ws + 168624192);    // 17 ints (+pad)
  int* ecnt     = (int*)   (ws + 168624264);    // 8 ints
  int* eoff     = (int*)   (ws + 168624296);    // 8 ints
  if (ws_size < 168624328) return;              // leave output poisoned -> clean failure

  hipMemsetAsync(counts2, 0, 2 * NE * sizeof(int), stream);

  cast_w_kernel<<<4096, 256, 0, stream>>>(wfc, wproj, wfcb, wpb);
  router_kernel<<<T_TOK / 4, 256, 0, stream>>>(x, wg, logits, xb, recI, recW, counts2);
  scan_kernel<<<1, 1, 0, stream>>>(counts2, offs2, ecnt, eoff);
  scatter_kernel<<<(T_TOK + 255) / 256, 256, 0, stream>>>(recI, recW, offs2, tok, aw);

  gemm1_kernel<<<NE * 64 * 8, 512, 0, stream>>>(xb, wfcb, tok, aw, ecnt, eoff, hglu);
  gemm2_kernel<<<NE * 32 * 8, 512, 0, stream>>>(hglu, wpb, tok, counts2, offs2, y, 0);
  gemm2_kernel<<<NE * 32 * 8, 512, 0, stream>>>(hglu, wpb, tok, counts2, offs2, y, 1);
}

// Round 6
// 814.100 us; speedup vs baseline: 1.1040x; 1.0373x over previous
//
#include <hip/hip_runtime.h>
#include <hip/hip_bf16.h>
#include <stdint.h>

// ---------------- problem constants ----------------
#define T_TOK 8192          // 4*2048 tokens
#define HID   2048          // hidden
#define IM    1024          // intermediate (GLU output)
#define NE    8             // experts

typedef __attribute__((ext_vector_type(8))) short bf16x8;   // 8 bf16 in 4 VGPRs
typedef __attribute__((ext_vector_type(4))) float f32x4;    // MFMA 16x16 accumulator

// async global->LDS, 16B per lane. LDS dest must be linear (base+lane*16);
// global src is per-lane (gather / pre-swizzle OK).
__device__ __forceinline__ void gload16(void* lds, const void* g) {
  __builtin_amdgcn_global_load_lds((const __attribute__((address_space(1))) char*)g,
                                   (__attribute__((address_space(3))) char*)lds, 16, 0, 0);
}

__device__ __forceinline__ ushort f2b(float f) {  // fp32 -> bf16 RNE bits
  union { float f; uint32_t u; } c; c.f = f;
  uint32_t u = c.u;
  return (ushort)((u + 0x7FFFu + ((u >> 16) & 1u)) >> 16);
}

#define MFMA16(a, b, c) __builtin_amdgcn_mfma_f32_16x16x32_bf16((a), (b), (c), 0, 0, 0)

// ---------------- cast fp32 -> bf16 for weights (merged) ----------------
__global__ void cast_w_kernel(const float* __restrict__ wfc, const float* __restrict__ wproj,
                              ushort* __restrict__ wfcb, ushort* __restrict__ wpb) {
  const int NFC4 = NE * 2 * IM * HID / 4;   // 8,388,608
  const int NPJ4 = NE * HID * IM / 4;       // 4,194,304
  int i = blockIdx.x * blockDim.x + threadIdx.x;
  int stride = gridDim.x * blockDim.x;
  for (; i < NFC4 + NPJ4; i += stride) {
    const float4* s; ushort4* d; int k;
    if (i < NFC4) { s = (const float4*)wfc;   d = (ushort4*)wfcb; k = i; }
    else          { s = (const float4*)wproj; d = (ushort4*)wpb;  k = i - NFC4; }
    float4 v = s[k];
    ushort4 o;
    o.x = f2b(v.x); o.y = f2b(v.y); o.z = f2b(v.z); o.w = f2b(v.w);
    d[k] = o;
  }
}

// ---------------- router: logits (fp64 accum), top-2, softmax; also emits xb ----------------
// Buckets are (expert, rank): bucket 2e = primary, bucket 2e+1 = secondary.
__global__ __launch_bounds__(256) void router_kernel(
    const float* __restrict__ x, const float* __restrict__ wg,
    float* __restrict__ logits_out, ushort* __restrict__ xb,
    int4* __restrict__ recI, float2* __restrict__ recW,
    int* __restrict__ counts2) {
  int wid = threadIdx.x >> 6, lane = threadIdx.x & 63;
  int tok = blockIdx.x * 4 + wid;
  if (tok >= T_TOK) return;
  const float4* xr = (const float4*)(x + (size_t)tok * HID);
  float4 xv[8];
#pragma unroll
  for (int j = 0; j < 8; ++j) xv[j] = xr[j * 64 + lane];
  // emit bf16 x row (saves a separate 67MB-read cast pass)
  ushort4* xbr = (ushort4*)(xb + (size_t)tok * HID);
#pragma unroll
  for (int j = 0; j < 8; ++j) {
    ushort4 o;
    o.x = f2b(xv[j].x); o.y = f2b(xv[j].y); o.z = f2b(xv[j].z); o.w = f2b(xv[j].w);
    xbr[j * 64 + lane] = o;
  }
  float lf[NE];
#pragma unroll
  for (int e = 0; e < NE; ++e) {
    const float4* wrow = (const float4*)(wg + (size_t)e * HID);
    double acc = 0.0;
#pragma unroll
    for (int j = 0; j < 8; ++j) {
      float4 w4 = wrow[j * 64 + lane];
      acc += (double)xv[j].x * w4.x + (double)xv[j].y * w4.y +
             (double)xv[j].z * w4.z + (double)xv[j].w * w4.w;
    }
#pragma unroll
    for (int off = 32; off; off >>= 1) acc += __shfl_xor(acc, off);
    lf[e] = (float)acc;
  }
  if (lane == 0) {
#pragma unroll
    for (int e = 0; e < NE; ++e) logits_out[(size_t)tok * NE + e] = lf[e];
    int i1 = 0;
#pragma unroll
    for (int e = 1; e < NE; ++e) if (lf[e] > lf[i1]) i1 = e;   // lowest idx on tie
    int i2 = -1;
#pragma unroll
    for (int e = 0; e < NE; ++e) {
      if (e == i1) continue;
      if (i2 < 0 || lf[e] > lf[i2]) i2 = e;
    }
    float t = expf(lf[i2] - lf[i1]);          // <= 1
    float w1 = 1.0f / (1.0f + t);
    float w2 = t / (1.0f + t);
    int s1 = atomicAdd(&counts2[i1 * 2 + 0], 1);
    int s2 = atomicAdd(&counts2[i2 * 2 + 1], 1);
    recI[tok] = make_int4(i1, s1, i2, s2);
    recW[tok] = make_float2(w1, w2);
  }
}

// wave-parallel 16-bucket exclusive scan (single 64-thread block)
__global__ void scan_kernel(const int* __restrict__ counts2, int* __restrict__ offs2,
                            int* __restrict__ ecnt, int* __restrict__ eoff) {
  int lane = threadIdx.x;   // 64 threads
  int c = (lane < 2 * NE) ? counts2[lane] : 0;
  int s = c;
#pragma unroll
  for (int d = 1; d < 16; d <<= 1) {
    int v = __shfl_up(s, d);
    if (lane >= d) s += v;
  }
  int excl = s - c;
  if (lane < 2 * NE) offs2[lane] = excl;
  if (lane == 2 * NE - 1) offs2[2 * NE] = s;
  int e2a = __shfl(excl, (lane & 7) * 2);
  int ca  = __shfl(c, (lane & 7) * 2);
  int cb  = __shfl(c, (lane & 7) * 2 + 1);
  if (lane < NE) { eoff[lane] = e2a; ecnt[lane] = ca + cb; }
}

__global__ void scatter_kernel(const int4* __restrict__ recI, const float2* __restrict__ recW,
                               const int* __restrict__ offs2,
                               int* __restrict__ tok_id, float* __restrict__ aw) {
  int t = blockIdx.x * blockDim.x + threadIdx.x;
  if (t >= T_TOK) return;
  int4 r = recI[t]; float2 w = recW[t];
  int p1 = offs2[r.x * 2 + 0] + r.y; tok_id[p1] = t; aw[p1] = w.x;
  int p2 = offs2[r.z * 2 + 1] + r.w; tok_id[p2] = t; aw[p2] = w.y;
}

// T2 swizzle: LDS row stride is 64B; reads of a column-16B-slice across rows are
// 8-way bank conflicts. Swizzled 16B-slot index gq = q ^ ((row>>1)&3) spreads 16
// consecutive rows over 8 banks (2-way = free). Write side pre-swizzles the
// GLOBAL source (gload_lds dest must stay linear); read side applies same XOR.

// ---------------- GEMM1 (CONTROL, unchanged from R5): gathered x @ w_fc_e^T, fused GLU ----
__global__ __launch_bounds__(512, 2) void gemm1_kernel(
    const ushort* __restrict__ xb, const ushort* __restrict__ wfcb,
    const int* __restrict__ tok_id, const float* __restrict__ aw,
    const int* __restrict__ ecnt, const int* __restrict__ eoff,
    ushort* __restrict__ hglu) {
  int bid = blockIdx.x;
  int e = bid >> 9;           // 8 experts
  int rt = (bid >> 3) & 63;   // up to 64 row tiles of 256
  int ct = bid & 7;           // 8 GLU col tiles of 128
  int cnt = ecnt[e];
  if (cnt == 0 || rt * 256 >= cnt) return;
  int off = eoff[e];
  int tid = threadIdx.x;

  __shared__ ushort lds[4][512 * 32];   // 128 KiB ring (A 256 | Ba 128 | Bb 128)

  int sslot[4]; const ushort* gsrc[4];
#pragma unroll
  for (int l = 0; l < 4; ++l) {
    int s = l * 512 + tid;
    int lrow = s >> 2, qs = s & 3;
    int gq = qs ^ ((lrow >> 1) & 3);
    sslot[l] = s * 8;
    if (l < 2) {
      int slotr = rt * 256 + lrow;
      if (slotr >= cnt) slotr = cnt - 1;
      gsrc[l] = xb + (size_t)tok_id[off + slotr] * HID + gq * 8;
    } else if (l == 2) {
      int fcr = e * 2048 + ct * 128 + (lrow - 256);
      gsrc[l] = wfcb + (size_t)fcr * HID + gq * 8;
    } else {
      int fcr = e * 2048 + 1024 + ct * 128 + (lrow - 384);
      gsrc[l] = wfcb + (size_t)fcr * HID + gq * 8;
    }
  }

  int wid = tid >> 6, lane = tid & 63;
  int wr = wid >> 2, wc = wid & 3;
  int q = lane >> 4, r = lane & 15;

  int offA[8], offBa[2], offBb[2];
#pragma unroll
  for (int m = 0; m < 8; ++m) {
    int lrow = wr * 128 + m * 16 + r;
    offA[m] = lrow * 32 + ((q ^ ((lrow >> 1) & 3)) << 3);
  }
#pragma unroll
  for (int n = 0; n < 2; ++n) {
    int lr1 = 256 + wc * 32 + n * 16 + r;
    offBa[n] = lr1 * 32 + ((q ^ ((lr1 >> 1) & 3)) << 3);
    int lr2 = 384 + wc * 32 + n * 16 + r;
    offBb[n] = lr2 * 32 + ((q ^ ((lr2 >> 1) & 3)) << 3);
  }

  f32x4 accA[8][2] = {}; f32x4 accB[8][2] = {};
  const int NT = HID / 32;   // 64

#define G1_STAGE(bufi, t, l) gload16(&lds[bufi][sslot[l]], gsrc[l] + (size_t)(t) * 32)
#pragma unroll
  for (int t = 0; t < 3; ++t) {
    G1_STAGE(t, t, 0); G1_STAGE(t, t, 1); G1_STAGE(t, t, 2); G1_STAGE(t, t, 3);
  }
  asm volatile("s_waitcnt vmcnt(8)" ::: "memory");
  __builtin_amdgcn_s_barrier();

  for (int t = 0; t < NT; ++t) {
    int cur = t & 3;
    const ushort* Bv = &lds[cur][0];
    int nb = (t + 3) & 3;
    bool pf = (t + 3) < NT;
    bf16x8 ba0 = *(const bf16x8*)&Bv[offBa[0]];
    bf16x8 ba1 = *(const bf16x8*)&Bv[offBa[1]];
    bf16x8 bb0 = *(const bf16x8*)&Bv[offBb[0]];
    bf16x8 bb1 = *(const bf16x8*)&Bv[offBb[1]];
    bf16x8 af[4];
#pragma unroll
    for (int m = 0; m < 4; ++m) af[m] = *(const bf16x8*)&Bv[offA[m]];
    if (pf) { G1_STAGE(nb, t + 3, 0); G1_STAGE(nb, t + 3, 1); }
    __builtin_amdgcn_s_barrier();
    __builtin_amdgcn_s_setprio(1);
#pragma unroll
    for (int m = 0; m < 4; ++m) {
      accA[m][0] = MFMA16(af[m], ba0, accA[m][0]);
      accA[m][1] = MFMA16(af[m], ba1, accA[m][1]);
      accB[m][0] = MFMA16(af[m], bb0, accB[m][0]);
      accB[m][1] = MFMA16(af[m], bb1, accB[m][1]);
    }
    __builtin_amdgcn_s_setprio(0);
    __builtin_amdgcn_s_barrier();
#pragma unroll
    for (int m = 0; m < 4; ++m) af[m] = *(const bf16x8*)&Bv[offA[4 + m]];
    if (pf) { G1_STAGE(nb, t + 3, 2); G1_STAGE(nb, t + 3, 3); }
    __builtin_amdgcn_s_barrier();
    __builtin_amdgcn_s_setprio(1);
#pragma unroll
    for (int m = 0; m < 4; ++m) {
      accA[4 + m][0] = MFMA16(af[m], ba0, accA[4 + m][0]);
      accA[4 + m][1] = MFMA16(af[m], ba1, accA[4 + m][1]);
      accB[4 + m][0] = MFMA16(af[m], bb0, accB[4 + m][0]);
      accB[4 + m][1] = MFMA16(af[m], bb1, accB[4 + m][1]);
    }
    __builtin_amdgcn_s_setprio(0);
    if (t < NT - 1) {
      if (t + 3 < NT)      asm volatile("s_waitcnt vmcnt(8)" ::: "memory");
      else if (t + 2 < NT) asm volatile("s_waitcnt vmcnt(4)" ::: "memory");
      else                 asm volatile("s_waitcnt vmcnt(0)" ::: "memory");
      __builtin_amdgcn_s_barrier();
    }
  }

#pragma unroll
  for (int m = 0; m < 8; ++m) {
#pragma unroll
    for (int j = 0; j < 4; ++j) {
      int slot = rt * 256 + wr * 128 + m * 16 + q * 4 + j;
      if (slot >= cnt) continue;
      float w = aw[off + slot];
      size_t rp = (size_t)(off + slot) * IM + ct * 128 + wc * 32 + r;
#pragma unroll
      for (int n = 0; n < 2; ++n) {
        float a = accA[m][n][j], b = accB[m][n][j];
        float g = (a / (1.0f + expf(-a))) * b * w;
        hglu[rp + n * 16] = f2b(g);
      }
    }
  }
}

// ---------------- GEMM2 (TREATMENT): m97-style 128x128, 256 thr, BK=32 dbuf ----------------
// Mechanism: 16 acc frags/wave -> ~130 regs -> 3-4 blocks/CU; inter-block TLP
// absorbs the per-tile barrier drain (m97/m114). Per pass ~1024 active blocks.
__global__ __launch_bounds__(256, 2) void gemm2_kernel(
    const ushort* __restrict__ hglu, const ushort* __restrict__ wpb,
    const int* __restrict__ tok_id,
    const int* __restrict__ counts2, const int* __restrict__ offs2,
    float* __restrict__ y, int pass) {
  int bid = blockIdx.x;
  int e = bid >> 10;          // 8 experts
  int rem = bid & 1023;
  int rt = rem >> 4;          // 64 row tiles of 128
  int ct = rem & 15;          // 16 col tiles of 128 over H=2048
  int cnt = counts2[2 * e + pass];
  if (cnt == 0 || rt * 128 >= cnt) return;
  int off = offs2[2 * e + pass];
  int tid = threadIdx.x;

  __shared__ ushort As[2][128 * 32];
  __shared__ ushort Bs[2][128 * 32];

  const ushort* gA[2]; const ushort* gB[2];
  int sslot[2];
#pragma unroll
  for (int p = 0; p < 2; ++p) {
    int s = p * 256 + tid;            // 0..511
    int row = s >> 2, qs = s & 3;
    int gq = qs ^ ((row >> 1) & 3);   // pre-swizzled global 16B-slot
    sslot[p] = s * 8;
    gA[p] = hglu + (size_t)(off + rt * 128 + row) * IM + gq * 8;   // pad-safe (see ws)
    gB[p] = wpb + (size_t)(e * 2048 + ct * 128 + row) * IM + gq * 8;
  }

  int wid = tid >> 6, lane = tid & 63;
  int wr = wid >> 1, wc = wid & 1;    // 2x2 waves, each 64x64
  int q = lane >> 4, r = lane & 15;

  int offA[4], offB[4];
#pragma unroll
  for (int m = 0; m < 4; ++m) {
    int row = wr * 64 + m * 16 + r;
    offA[m] = row * 32 + ((q ^ ((row >> 1) & 3)) << 3);
  }
#pragma unroll
  for (int n = 0; n < 4; ++n) {
    int row = wc * 64 + n * 16 + r;
    offB[n] = row * 32 + ((q ^ ((row >> 1) & 3)) << 3);
  }

  f32x4 acc[4][4] = {};
  const int NT = IM / 32;   // 32

  auto stage = [&](int b, int kt) {
#pragma unroll
    for (int p = 0; p < 2; ++p) {
      gload16(&As[b][sslot[p]], gA[p] + (size_t)kt * 32);
      gload16(&Bs[b][sslot[p]], gB[p] + (size_t)kt * 32);
    }
  };

  stage(0, 0);
  __syncthreads();
  for (int kt = 0; kt < NT; ++kt) {
    int cur = kt & 1;
    if (kt < NT - 1) stage(cur ^ 1, kt + 1);
    bf16x8 af[4], bf[4];
#pragma unroll
    for (int m = 0; m < 4; ++m) af[m] = *(const bf16x8*)&As[cur][offA[m]];
#pragma unroll
    for (int n = 0; n < 4; ++n) bf[n] = *(const bf16x8*)&Bs[cur][offB[n]];
#pragma unroll
    for (int m = 0; m < 4; ++m)
#pragma unroll
      for (int n = 0; n < 4; ++n)
        acc[m][n] = MFMA16(af[m], bf[n], acc[m][n]);
    __syncthreads();
  }

#pragma unroll
  for (int m = 0; m < 4; ++m) {
#pragma unroll
    for (int j = 0; j < 4; ++j) {
      int slot = rt * 128 + wr * 64 + m * 16 + q * 4 + j;
      if (slot >= cnt) continue;
      int tok = tok_id[off + slot];
      float* yp = &y[(size_t)tok * HID + ct * 128 + wc * 64 + r];
      if (pass == 0) {
#pragma unroll
        for (int n = 0; n < 4; ++n) yp[n * 16] = acc[m][n][j];
      } else {
#pragma unroll
        for (int n = 0; n < 4; ++n) yp[n * 16] += acc[m][n][j];
      }
    }
  }
}

// ---------------- launch ----------------
extern "C" void kernel_launch(void* const* d_in, const int* in_sizes, int n_in,
                              void* d_out, int out_size, void* d_ws, size_t ws_size,
                              hipStream_t stream) {
  const float* x     = (const float*)d_in[0];
  const float* wg    = (const float*)d_in[1];
  const float* wfc   = (const float*)d_in[2];
  const float* wproj = (const float*)d_in[3];
  float* y = (float*)d_out;
  float* logits = y + (size_t)T_TOK * HID;

  // workspace layout (bytes)
  char* ws = (char*)d_ws;
  ushort* xb    = (ushort*)(ws + 0);            // 33,554,432
  ushort* wfcb  = (ushort*)(ws + 33554432);     // 67,108,864
  ushort* wpb   = (ushort*)(ws + 100663296);    // 33,554,432
  ushort* hglu  = (ushort*)(ws + 134217728);    // (16384+256)*1024*2 = 34,078,720
  int*    tok   = (int*)   (ws + 168296448);    // 65,536
  float*  aw    = (float*) (ws + 168361984);    // 65,536
  int4*   recI  = (int4*)  (ws + 168427520);    // 131,072
  float2* recW  = (float2*)(ws + 168558592);    // 65,536
  int* counts2  = (int*)   (ws + 168624128);    // 16 ints
  int* offs2    = (int*)   (ws + 168624192);    // 17 ints (+pad)
  int* ecnt     = (int*)   (ws + 168624264);    // 8 ints
  int* eoff     = (int*)   (ws + 168624296);    // 8 ints
  if (ws_size < 168624328) return;              // leave output poisoned -> clean failure

  hipMemsetAsync(counts2, 0, 2 * NE * sizeof(int), stream);

  cast_w_kernel<<<4096, 256, 0, stream>>>(wfc, wproj, wfcb, wpb);
  router_kernel<<<T_TOK / 4, 256, 0, stream>>>(x, wg, logits, xb, recI, recW, counts2);
  scan_kernel<<<1, 64, 0, stream>>>(counts2, offs2, ecnt, eoff);
  scatter_kernel<<<(T_TOK + 255) / 256, 256, 0, stream>>>(recI, recW, offs2, tok, aw);

  gemm1_kernel<<<NE * 64 * 8, 512, 0, stream>>>(xb, wfcb, tok, aw, ecnt, eoff, hglu);
  gemm2_kernel<<<NE * 64 * 16, 256, 0, stream>>>(hglu, wpb, tok, counts2, offs2, y, 0);
  gemm2_kernel<<<NE * 64 * 16, 256, 0, stream>>>(hglu, wpb, tok, counts2, offs2, y, 1);
}